// Round 4
// baseline (463.547 us; speedup 1.0000x reference)
//
#include <hip/hip_runtime.h>

#define NN 50000
#define NE 800000
#define BG 512
#define HD 128
#define GD 32
#define MD 128
#define EPSV 1e-5f
#define NBK 256   // dst buckets
#define BSTR 196  // dst per bucket (196*256 = 50176 >= NN)
#define BCAP 4096 // edge capacity per bucket (mean 3136, sd ~56)
#define SP 136    // LDS row stride (shorts) for gemm tiles
#define NSC 64    // stats partial copies (contention 12500/64 ~ 195/addr)

typedef __attribute__((ext_vector_type(8))) short bf16x8;
typedef __attribute__((ext_vector_type(4))) float f32x4;

// bf16 helpers (RNE pack, cheap unpack)
static __device__ __forceinline__ unsigned short f2bf(float f) {
    unsigned int u = __float_as_uint(f);
    u += 0x7fffu + ((u >> 16) & 1u);
    return (unsigned short)(u >> 16);
}
static __device__ __forceinline__ float bfu(unsigned short v) {
    return __uint_as_float((unsigned int)v << 16);
}
static __device__ __forceinline__ float bf_lo(unsigned int v) {
    return __uint_as_float(v << 16);
}
static __device__ __forceinline__ float bf_hi(unsigned int v) {
    return __uint_as_float(v & 0xffff0000u);
}

// ---------------- Pass 1: bin edges by dst bucket ----------------
__global__ __launch_bounds__(256) void k_bin(const int* __restrict__ src,
                                             const int* __restrict__ dst,
                                             int* __restrict__ bucket_cnt,
                                             unsigned int* __restrict__ binned) {
    __shared__ int hcnt[NBK];
    __shared__ int hbase[NBK];
    int tid = threadIdx.x;
    int e0 = blockIdx.x * 2048;
    unsigned int pv[8];
    int bk[8], rk[8];
#pragma unroll
    for (int i = 0; i < 8; ++i) {
        int e = e0 + i * 256 + tid;
        if (e < NE) {
            int s = src[e];
            int d = dst[e];
            bk[i] = d / BSTR;
            pv[i] = ((unsigned int)(d - bk[i] * BSTR) << 16) | (unsigned int)s;
        } else {
            bk[i] = -1;
        }
    }
    hcnt[tid] = 0;
    __syncthreads();
#pragma unroll
    for (int i = 0; i < 8; ++i)
        if (bk[i] >= 0) rk[i] = atomicAdd(&hcnt[bk[i]], 1);
    __syncthreads();
    hbase[tid] = atomicAdd(&bucket_cnt[tid], hcnt[tid]);
    __syncthreads();
#pragma unroll
    for (int i = 0; i < 8; ++i)
        if (bk[i] >= 0)
            binned[(size_t)bk[i] * BCAP + hbase[bk[i]] + rk[i]] = pv[i];
}

// ---------------- CSR build (blocks 0..255) + W transpose (blocks 256..258) ----------------
__global__ __launch_bounds__(256) void k_csr(const unsigned int* __restrict__ binned,
                                             const int* __restrict__ bucket_cnt,
                                             int* __restrict__ offsets,
                                             float* __restrict__ dinv,
                                             int* __restrict__ csr,
                                             const float* __restrict__ W0,
                                             const float* __restrict__ W1,
                                             const float* __restrict__ W2,
                                             unsigned short* __restrict__ Wt) {
    __shared__ unsigned short sW[128 * 130];
    __shared__ int ls[256];
    __shared__ int h[BSTR];
    __shared__ int cur[BSTR];
    __shared__ int bpre_s;
    int b = blockIdx.x, t = threadIdx.x;
    if (b >= NBK) {
        const float* Wsrc = (b == NBK) ? W0 : ((b == NBK + 1) ? W1 : W2);
#pragma unroll
        for (int i = 0; i < 64; ++i) {
            int idx = i * 256 + t;
            int k = idx >> 7, n = idx & 127;
            sW[n * 130 + k] = f2bf(Wsrc[idx]);
        }
        __syncthreads();
        unsigned short* o = Wt + (size_t)(b - NBK) * 16384;
#pragma unroll
        for (int i = 0; i < 64; ++i) {
            int idx = i * 256 + t;
            int n = idx >> 7, k = idx & 127;
            o[idx] = sW[n * 130 + k];
        }
        return;
    }
    int bc = bucket_cnt[t];
    ls[t] = bc;
    __syncthreads();
    for (int off = 1; off < 256; off <<= 1) {
        int c0 = ls[t];
        int add = (t >= off) ? ls[t - off] : 0;
        __syncthreads();
        ls[t] = c0 + add;
        __syncthreads();
    }
    if (t == b) bpre_s = ls[t] - bc;
    if (t < BSTR) h[t] = 0;
    __syncthreads();
    int bpre = bpre_s;
    int nb = bucket_cnt[b];
    const unsigned int* base = binned + (size_t)b * BCAP;
    for (int e = t; e < nb; e += 256)
        atomicAdd(&h[base[e] >> 16], 1);
    __syncthreads();
    int c = (t < BSTR) ? h[t] : 0;
    ls[t] = c;
    __syncthreads();
    for (int off = 1; off < 256; off <<= 1) {
        int c0 = ls[t];
        int add = (t >= off) ? ls[t - off] : 0;
        __syncthreads();
        ls[t] = c0 + add;
        __syncthreads();
    }
    int node = b * BSTR + t;
    if (t < BSTR) {
        int excl = ls[t] - c + bpre;
        cur[t] = excl;
        if (node < NN) {
            offsets[node] = excl;
            dinv[node] = rsqrtf((float)(c + 1));  // in-degree + self loop
            if (node == NN - 1) offsets[NN] = NE;
        }
    }
    __syncthreads();
    for (int e = t; e < nb; e += 256) {
        unsigned int v = base[e];
        int pos = atomicAdd(&cur[v >> 16], 1);
        csr[pos] = (int)(v & 0xffffu);
    }
}

// ---------------- MFMA GEMM (LDS-staged): Th(bf16) = dinv[row] * (BNReLU?(In) @ W) ----------------
// BN scales derived from 64-copy partial stats (reduced here, once per block).
__global__ __launch_bounds__(256) void k_gemm(const float* __restrict__ Inf,
                                              const unsigned short* __restrict__ Inh,
                                              const unsigned short* __restrict__ Wt,
                                              unsigned short* __restrict__ Th,
                                              const float* __restrict__ statsP,
                                              const float* __restrict__ gamma,
                                              const float* __restrict__ beta,
                                              const float* __restrict__ dinv,
                                              int useBN) {
    __shared__ unsigned short Abf[64 * SP];
    __shared__ unsigned short WtL[128 * SP];
    __shared__ float ssS[256];
    int tid = threadIdx.x;
    int rowBase = blockIdx.x * 64;
    if (useBN) {
        float s = 0.f;
        for (int c = 0; c < NSC; ++c) s += statsP[c * 256 + tid];
        ssS[tid] = s;
        __syncthreads();
        if (tid < 128) {
            float mu = ssS[tid] * (1.f / NN);
            float var = ssS[128 + tid] * (1.f / NN) - mu * mu;
            float sc = gamma[tid] * rsqrtf(var + EPSV);
            float sh = beta[tid] - mu * sc;
            ssS[tid] = sc;
            ssS[128 + tid] = sh;
        }
        __syncthreads();
#pragma unroll
        for (int i = 0; i < 4; ++i) {
            int q = tid + i * 256;   // 0..1023
            int row = q >> 4;
            int k8 = (q & 15) * 8;
            int rg = rowBase + row;
            if (rg >= NN) rg = NN - 1;
            bf16x8 raw = *(const bf16x8*)&Inh[(size_t)rg * HD + k8];
            unsigned short o[8];
#pragma unroll
            for (int e = 0; e < 8; ++e) {
                float v = bfu((unsigned short)raw[e]);
                v = fmaxf(v * ssS[k8 + e] + ssS[128 + k8 + e], 0.f);
                o[e] = f2bf(v);
            }
            *(bf16x8*)&Abf[row * SP + k8] = *(bf16x8*)o;
        }
    } else {
#pragma unroll
        for (int i = 0; i < 8; ++i) {
            int q = tid + i * 256;   // float4 units
            int row = q >> 5;
            int c4 = (q & 31) * 4;
            int rg = rowBase + row;
            if (rg >= NN) rg = NN - 1;
            float4 v = *(const float4*)&Inf[(size_t)rg * HD + c4];
            unsigned short* p = &Abf[row * SP + c4];
            p[0] = f2bf(v.x); p[1] = f2bf(v.y); p[2] = f2bf(v.z); p[3] = f2bf(v.w);
        }
    }
#pragma unroll
    for (int i = 0; i < 8; ++i) {
        int q = tid + i * 256;   // short8 units
        int n = q >> 4;
        int k8 = (q & 15) * 8;
        bf16x8 w = *(const bf16x8*)&Wt[n * HD + k8];
        *(bf16x8*)&WtL[n * SP + k8] = w;
    }
    __syncthreads();
    int lane = tid & 63;
    int wv = tid >> 6;
    int quad = lane >> 4;
    int lrow = wv * 16 + (lane & 15);
    f32x4 acc[8];
#pragma unroll
    for (int c = 0; c < 8; ++c) acc[c] = (f32x4){0.f, 0.f, 0.f, 0.f};
#pragma unroll
    for (int qk = 0; qk < 4; ++qk) {
        int ko = quad * 8 + qk * 32;
        bf16x8 bfr = *(const bf16x8*)&Abf[lrow * SP + ko];
#pragma unroll
        for (int c = 0; c < 8; ++c) {
            bf16x8 afr = *(const bf16x8*)&WtL[(c * 16 + (lane & 15)) * SP + ko];
            acc[c] = __builtin_amdgcn_mfma_f32_16x16x32_bf16(afr, bfr, acc[c], 0, 0, 0);
        }
    }
    int grow = rowBase + lrow;
    if (grow < NN) {
        float di = dinv[grow];
#pragma unroll
        for (int c = 0; c < 8; ++c) {
            ushort4 o;
            o.x = f2bf(acc[c][0] * di);
            o.y = f2bf(acc[c][1] * di);
            o.z = f2bf(acc[c][2] * di);
            o.w = f2bf(acc[c][3] * di);
            *(ushort4*)&Th[(size_t)grow * HD + c * 16 + quad * 4] = o;
        }
    }
}

// ---------------- Aggregate + fused BN column stats ----------------
// A(bf16)[d] = dinv[d]*(sum Ts[s] + Ts[d]) + b ; pre-round f32 values feed
// sum/sumsq via LDS atomics -> one global atomicAdd per thread into
// statsP[blockIdx&63][256].
__global__ __launch_bounds__(256, 8) void k_aggregate(const uint4* __restrict__ T4,
                                                      const int* __restrict__ offsets,
                                                      const int* __restrict__ csr,
                                                      const float* __restrict__ dinv,
                                                      const float* __restrict__ bias,
                                                      unsigned short* __restrict__ Ah,
                                                      float* __restrict__ statsP) {
    __shared__ float sst[256];
    int tid = threadIdx.x;
    sst[tid] = 0.f;
    __syncthreads();
    int d = blockIdx.x * 4 + (tid >> 6);
    int l = tid & 63;
    int half = l >> 4;   // 0..3 : edge slot
    int li = l & 15;     // uint4 index within a 128-feat row
    if (d < NN) {
        int start = offsets[d], end = offsets[d + 1];
        float a0 = 0.f, a1 = 0.f, a2 = 0.f, a3 = 0.f;
        float a4 = 0.f, a5 = 0.f, a6 = 0.f, a7 = 0.f;
        int j = start;
        for (; j + 7 < end; j += 8) {
            int s0 = csr[j + half];
            int s1 = csr[j + 4 + half];
            uint4 v0 = T4[(size_t)s0 * 16 + li];
            uint4 v1 = T4[(size_t)s1 * 16 + li];
            a0 += bf_lo(v0.x); a1 += bf_hi(v0.x); a2 += bf_lo(v0.y); a3 += bf_hi(v0.y);
            a4 += bf_lo(v0.z); a5 += bf_hi(v0.z); a6 += bf_lo(v0.w); a7 += bf_hi(v0.w);
            a0 += bf_lo(v1.x); a1 += bf_hi(v1.x); a2 += bf_lo(v1.y); a3 += bf_hi(v1.y);
            a4 += bf_lo(v1.z); a5 += bf_hi(v1.z); a6 += bf_lo(v1.w); a7 += bf_hi(v1.w);
        }
        for (; j + 3 < end; j += 4) {
            int s0 = csr[j + half];
            uint4 v0 = T4[(size_t)s0 * 16 + li];
            a0 += bf_lo(v0.x); a1 += bf_hi(v0.x); a2 += bf_lo(v0.y); a3 += bf_hi(v0.y);
            a4 += bf_lo(v0.z); a5 += bf_hi(v0.z); a6 += bf_lo(v0.w); a7 += bf_hi(v0.w);
        }
        if (j + half < end) {
            int s0 = csr[j + half];
            uint4 v0 = T4[(size_t)s0 * 16 + li];
            a0 += bf_lo(v0.x); a1 += bf_hi(v0.x); a2 += bf_lo(v0.y); a3 += bf_hi(v0.y);
            a4 += bf_lo(v0.z); a5 += bf_hi(v0.z); a6 += bf_lo(v0.w); a7 += bf_hi(v0.w);
        }
        // reduce across the 4 edge slots (lanes l, l^16, l^32, l^48)
        a0 += __shfl_xor(a0, 16); a1 += __shfl_xor(a1, 16);
        a2 += __shfl_xor(a2, 16); a3 += __shfl_xor(a3, 16);
        a4 += __shfl_xor(a4, 16); a5 += __shfl_xor(a5, 16);
        a6 += __shfl_xor(a6, 16); a7 += __shfl_xor(a7, 16);
        a0 += __shfl_xor(a0, 32); a1 += __shfl_xor(a1, 32);
        a2 += __shfl_xor(a2, 32); a3 += __shfl_xor(a3, 32);
        a4 += __shfl_xor(a4, 32); a5 += __shfl_xor(a5, 32);
        a6 += __shfl_xor(a6, 32); a7 += __shfl_xor(a7, 32);
        if (half == 0) {
            float di = dinv[d];
            uint4 vd = T4[(size_t)d * 16 + li];
            float4 bs0 = *(const float4*)&bias[8 * li];
            float4 bs1 = *(const float4*)&bias[8 * li + 4];
            float v0 = di * (a0 + bf_lo(vd.x)) + bs0.x;
            float v1 = di * (a1 + bf_hi(vd.x)) + bs0.y;
            float v2 = di * (a2 + bf_lo(vd.y)) + bs0.z;
            float v3 = di * (a3 + bf_hi(vd.y)) + bs0.w;
            float v4 = di * (a4 + bf_lo(vd.z)) + bs1.x;
            float v5 = di * (a5 + bf_hi(vd.z)) + bs1.y;
            float v6 = di * (a6 + bf_lo(vd.w)) + bs1.z;
            float v7 = di * (a7 + bf_hi(vd.w)) + bs1.w;
            int fb = 8 * li;
            atomicAdd(&sst[fb + 0], v0); atomicAdd(&sst[fb + 1], v1);
            atomicAdd(&sst[fb + 2], v2); atomicAdd(&sst[fb + 3], v3);
            atomicAdd(&sst[fb + 4], v4); atomicAdd(&sst[fb + 5], v5);
            atomicAdd(&sst[fb + 6], v6); atomicAdd(&sst[fb + 7], v7);
            atomicAdd(&sst[128 + fb + 0], v0 * v0); atomicAdd(&sst[128 + fb + 1], v1 * v1);
            atomicAdd(&sst[128 + fb + 2], v2 * v2); atomicAdd(&sst[128 + fb + 3], v3 * v3);
            atomicAdd(&sst[128 + fb + 4], v4 * v4); atomicAdd(&sst[128 + fb + 5], v5 * v5);
            atomicAdd(&sst[128 + fb + 6], v6 * v6); atomicAdd(&sst[128 + fb + 7], v7 * v7);
            unsigned short o[8];
            o[0] = f2bf(v0); o[1] = f2bf(v1); o[2] = f2bf(v2); o[3] = f2bf(v3);
            o[4] = f2bf(v4); o[5] = f2bf(v5); o[6] = f2bf(v6); o[7] = f2bf(v7);
            *(bf16x8*)&Ah[(size_t)d * HD + 8 * li] = *(bf16x8*)o;
        }
    }
    __syncthreads();
    atomicAdd(&statsP[(blockIdx.x & (NSC - 1)) * 256 + tid], sst[tid]);
}

// ---------------- MLP head with fused pool + BN (one graph per block) ----------------
__global__ __launch_bounds__(128) void k_mlp(const unsigned short* __restrict__ Ah,
                                             const int* __restrict__ batch,
                                             const float* __restrict__ statsP,
                                             const float* __restrict__ gamma,
                                             const float* __restrict__ beta,
                                             const float* __restrict__ gfeat,
                                             const float* __restrict__ M1w,
                                             const float* __restrict__ M1b,
                                             const float* __restrict__ M2w,
                                             const float* __restrict__ M2b,
                                             const float* __restrict__ M3w,
                                             const float* __restrict__ M3b,
                                             float* __restrict__ out) {
    __shared__ int sb[2];
    __shared__ float ssc[128], ssh[128];
    __shared__ float zp[4][128];
    __shared__ float z[HD + GD];
    __shared__ float z1[MD];
    __shared__ float z2[MD / 2];
    int b = blockIdx.x, t = threadIdx.x;
    if (t < 2) {
        int val = b + t;
        int lo = 0, hi = NN;
        while (lo < hi) {
            int mid = (lo + hi) >> 1;
            if (batch[mid] < val) lo = mid + 1; else hi = mid;
        }
        sb[t] = lo;
    }
    // BN scales for layer-2 stats (feat t)
    float s = 0.f, q = 0.f;
    for (int c = 0; c < NSC; ++c) {
        s += statsP[c * 256 + t];
        q += statsP[c * 256 + 128 + t];
    }
    {
        float mu = s * (1.f / NN);
        float var = q * (1.f / NN) - mu * mu;
        float sc = gamma[t] * rsqrtf(var + EPSV);
        ssc[t] = sc;
        ssh[t] = beta[t] - mu * sc;
    }
    __syncthreads();
    int s0 = sb[0], s1 = sb[1];
    int grp = t >> 5, u = t & 31;
    float c0 = ssc[4 * u], c1 = ssc[4 * u + 1], c2 = ssc[4 * u + 2], c3 = ssc[4 * u + 3];
    float h0 = ssh[4 * u], h1 = ssh[4 * u + 1], h2 = ssh[4 * u + 2], h3 = ssh[4 * u + 3];
    float p0 = 0.f, p1 = 0.f, p2 = 0.f, p3 = 0.f;
    const uint2* A2 = (const uint2*)Ah;
    for (int r = s0 + grp; r < s1; r += 4) {
        uint2 v = A2[(size_t)r * 32 + u];
        p0 += fmaxf(bf_lo(v.x) * c0 + h0, 0.f);
        p1 += fmaxf(bf_hi(v.x) * c1 + h1, 0.f);
        p2 += fmaxf(bf_lo(v.y) * c2 + h2, 0.f);
        p3 += fmaxf(bf_hi(v.y) * c3 + h3, 0.f);
    }
    zp[grp][4 * u + 0] = p0;
    zp[grp][4 * u + 1] = p1;
    zp[grp][4 * u + 2] = p2;
    zp[grp][4 * u + 3] = p3;
    __syncthreads();
    float ic = 1.f / fmaxf((float)(s1 - s0), 1.f);
    z[t] = (zp[0][t] + zp[1][t] + zp[2][t] + zp[3][t]) * ic;
    if (t < GD) z[HD + t] = gfeat[b * GD + t];
    __syncthreads();
    float a = M1b[t];
    for (int k = 0; k < HD + GD; ++k) a += z[k] * M1w[k * MD + t];
    z1[t] = fmaxf(a, 0.f);
    __syncthreads();
    if (t < MD / 2) {
        float a2 = M2b[t];
        for (int k = 0; k < MD; ++k) a2 += z1[k] * M2w[k * (MD / 2) + t];
        z2[t] = fmaxf(a2, 0.f);
    }
    __syncthreads();
    if (t < 64) {
        float p = z2[t] * M3w[t];
#pragma unroll
        for (int off = 32; off; off >>= 1) p += __shfl_down(p, off);
        if (t == 0) out[b] = p + M3b[0];
    }
}

static inline size_t alg(size_t x) { return (x + 255) & ~(size_t)255; }

extern "C" void kernel_launch(void* const* d_in, const int* in_sizes, int n_in,
                              void* d_out, int out_size, void* d_ws, size_t ws_size,
                              hipStream_t stream) {
    const float* x = (const float*)d_in[0];
    const int* ei = (const int*)d_in[1];
    const int* batch = (const int*)d_in[2];
    const float* gf = (const float*)d_in[3];
    const float* W[3] = {(const float*)d_in[4], (const float*)d_in[8], (const float*)d_in[12]};
    const float* bb[3] = {(const float*)d_in[5], (const float*)d_in[9], (const float*)d_in[13]};
    const float* gg[3] = {(const float*)d_in[6], (const float*)d_in[10], (const float*)d_in[14]};
    const float* be[3] = {(const float*)d_in[7], (const float*)d_in[11], (const float*)d_in[15]};
    const float* M1w = (const float*)d_in[16];
    const float* M1b = (const float*)d_in[17];
    const float* M2w = (const float*)d_in[18];
    const float* M2b = (const float*)d_in[19];
    const float* M3w = (const float*)d_in[20];
    const float* M3b = (const float*)d_in[21];
    float* out = (float*)d_out;

    char* w = (char*)d_ws;
    int* bucket_cnt = (int*)w;    w += alg((size_t)NBK * 4);
    float* statsP = (float*)w;    w += alg((size_t)3 * NSC * 256 * 4);
    size_t zspan = (size_t)(w - (char*)d_ws);   // zero bucket_cnt+statsP in one fill
    int* offsets = (int*)w;       w += alg((size_t)(NN + 1) * 4);
    int* csr = (int*)w;           w += alg((size_t)NE * 4);
    float* dinv = (float*)w;      w += alg((size_t)NN * 4);
    unsigned short* Wt = (unsigned short*)w;  w += alg((size_t)3 * 16384 * 2);
    unsigned int* binned = (unsigned int*)w;  w += alg((size_t)NBK * BCAP * 4);
    unsigned short* Ah = (unsigned short*)w;  w += alg((size_t)NN * HD * 2);
    unsigned short* Th = (unsigned short*)w;  w += alg((size_t)NN * HD * 2);

    const int* src = ei;
    const int* dst = ei + NE;

    hipMemsetAsync(bucket_cnt, 0, zspan, stream);
    k_bin<<<(NE + 2047) / 2048, 256, 0, stream>>>(src, dst, bucket_cnt, binned);
    k_csr<<<NBK + 3, 256, 0, stream>>>(binned, bucket_cnt, offsets, dinv, csr,
                                       W[0], W[1], W[2], Wt);

    for (int L = 0; L < 3; ++L) {
        k_gemm<<<(NN + 63) / 64, 256, 0, stream>>>(x, Ah, Wt + (size_t)L * 16384, Th,
                                                   statsP + (L ? (L - 1) * NSC * 256 : 0),
                                                   gg[L ? L - 1 : 0], be[L ? L - 1 : 0],
                                                   dinv, L > 0);
        k_aggregate<<<(NN + 3) / 4, 256, 0, stream>>>((const uint4*)Th, offsets, csr,
                                                      dinv, bb[L], Ah,
                                                      statsP + (size_t)L * NSC * 256);
    }

    k_mlp<<<BG, 128, 0, stream>>>(Ah, batch, statsP + (size_t)2 * NSC * 256,
                                  gg[2], be[2], gf, M1w, M1b, M2w, M2b, M3w, M3b, out);
}

// Round 5
// 317.642 us; speedup vs baseline: 1.4593x; 1.4593x over previous
//
#include <hip/hip_runtime.h>

#define NN 50000
#define NE 800000
#define BG 512
#define HD 128
#define GD 32
#define MD 128
#define EPSV 1e-5f
#define NBK 256   // dst buckets
#define BSTR 196  // dst per bucket (196*256 = 50176 >= NN)
#define BCAP 4096 // edge capacity per bucket (mean 3136, sd ~56)
#define SP 136    // LDS row stride (shorts) for gemm tiles
#define NSC 64    // stats partial copies (contention 12500/64 ~ 195/addr)

typedef __attribute__((ext_vector_type(8))) short bf16x8;
typedef __attribute__((ext_vector_type(4))) float f32x4;

// bf16 helpers (RNE pack, cheap unpack)
static __device__ __forceinline__ unsigned short f2bf(float f) {
    unsigned int u = __float_as_uint(f);
    u += 0x7fffu + ((u >> 16) & 1u);
    return (unsigned short)(u >> 16);
}
static __device__ __forceinline__ float bfu(unsigned short v) {
    return __uint_as_float((unsigned int)v << 16);
}
static __device__ __forceinline__ float bf_lo(unsigned int v) {
    return __uint_as_float(v << 16);
}
static __device__ __forceinline__ float bf_hi(unsigned int v) {
    return __uint_as_float(v & 0xffff0000u);
}

// ---------------- Pass 1: bin edges by dst bucket ----------------
__global__ __launch_bounds__(256) void k_bin(const int* __restrict__ src,
                                             const int* __restrict__ dst,
                                             int* __restrict__ bucket_cnt,
                                             unsigned int* __restrict__ binned) {
    __shared__ int hcnt[NBK];
    __shared__ int hbase[NBK];
    int tid = threadIdx.x;
    int e0 = blockIdx.x * 2048;
    unsigned int pv[8];
    int bk[8], rk[8];
#pragma unroll
    for (int i = 0; i < 8; ++i) {
        int e = e0 + i * 256 + tid;
        if (e < NE) {
            int s = src[e];
            int d = dst[e];
            bk[i] = d / BSTR;
            pv[i] = ((unsigned int)(d - bk[i] * BSTR) << 16) | (unsigned int)s;
        } else {
            bk[i] = -1;
        }
    }
    hcnt[tid] = 0;
    __syncthreads();
#pragma unroll
    for (int i = 0; i < 8; ++i)
        if (bk[i] >= 0) rk[i] = atomicAdd(&hcnt[bk[i]], 1);
    __syncthreads();
    hbase[tid] = atomicAdd(&bucket_cnt[tid], hcnt[tid]);
    __syncthreads();
#pragma unroll
    for (int i = 0; i < 8; ++i)
        if (bk[i] >= 0)
            binned[(size_t)bk[i] * BCAP + hbase[bk[i]] + rk[i]] = pv[i];
}

// ---------------- CSR build (blocks 0..255) + W transpose (blocks 256..258) ----------------
__global__ __launch_bounds__(256) void k_csr(const unsigned int* __restrict__ binned,
                                             const int* __restrict__ bucket_cnt,
                                             int* __restrict__ offsets,
                                             float* __restrict__ dinv,
                                             int* __restrict__ csr,
                                             const float* __restrict__ W0,
                                             const float* __restrict__ W1,
                                             const float* __restrict__ W2,
                                             unsigned short* __restrict__ Wt) {
    __shared__ unsigned short sW[128 * 130];
    __shared__ int ls[256];
    __shared__ int h[BSTR];
    __shared__ int cur[BSTR];
    __shared__ int bpre_s;
    int b = blockIdx.x, t = threadIdx.x;
    if (b >= NBK) {
        const float* Wsrc = (b == NBK) ? W0 : ((b == NBK + 1) ? W1 : W2);
#pragma unroll
        for (int i = 0; i < 64; ++i) {
            int idx = i * 256 + t;
            int k = idx >> 7, n = idx & 127;
            sW[n * 130 + k] = f2bf(Wsrc[idx]);
        }
        __syncthreads();
        unsigned short* o = Wt + (size_t)(b - NBK) * 16384;
#pragma unroll
        for (int i = 0; i < 64; ++i) {
            int idx = i * 256 + t;
            int n = idx >> 7, k = idx & 127;
            o[idx] = sW[n * 130 + k];
        }
        return;
    }
    int bc = bucket_cnt[t];
    ls[t] = bc;
    __syncthreads();
    for (int off = 1; off < 256; off <<= 1) {
        int c0 = ls[t];
        int add = (t >= off) ? ls[t - off] : 0;
        __syncthreads();
        ls[t] = c0 + add;
        __syncthreads();
    }
    if (t == b) bpre_s = ls[t] - bc;
    if (t < BSTR) h[t] = 0;
    __syncthreads();
    int bpre = bpre_s;
    int nb = bucket_cnt[b];
    const unsigned int* base = binned + (size_t)b * BCAP;
    for (int e = t; e < nb; e += 256)
        atomicAdd(&h[base[e] >> 16], 1);
    __syncthreads();
    int c = (t < BSTR) ? h[t] : 0;
    ls[t] = c;
    __syncthreads();
    for (int off = 1; off < 256; off <<= 1) {
        int c0 = ls[t];
        int add = (t >= off) ? ls[t - off] : 0;
        __syncthreads();
        ls[t] = c0 + add;
        __syncthreads();
    }
    int node = b * BSTR + t;
    if (t < BSTR) {
        int excl = ls[t] - c + bpre;
        cur[t] = excl;
        if (node < NN) {
            offsets[node] = excl;
            dinv[node] = rsqrtf((float)(c + 1));  // in-degree + self loop
            if (node == NN - 1) offsets[NN] = NE;
        }
    }
    __syncthreads();
    for (int e = t; e < nb; e += 256) {
        unsigned int v = base[e];
        int pos = atomicAdd(&cur[v >> 16], 1);
        csr[pos] = (int)(v & 0xffffu);
    }
}

// ---------------- MFMA GEMM (LDS-staged): Th(bf16) = dinv[row] * (BNReLU?(In) @ W) ----------------
// BN scales derived from 64-copy partial stats (reduced here, once per block).
__global__ __launch_bounds__(256) void k_gemm(const float* __restrict__ Inf,
                                              const unsigned short* __restrict__ Inh,
                                              const unsigned short* __restrict__ Wt,
                                              unsigned short* __restrict__ Th,
                                              const float* __restrict__ statsP,
                                              const float* __restrict__ gamma,
                                              const float* __restrict__ beta,
                                              const float* __restrict__ dinv,
                                              int useBN) {
    __shared__ unsigned short Abf[64 * SP];
    __shared__ unsigned short WtL[128 * SP];
    __shared__ float ssS[256];
    int tid = threadIdx.x;
    int rowBase = blockIdx.x * 64;
    if (useBN) {
        float s = 0.f;
        for (int c = 0; c < NSC; ++c) s += statsP[c * 256 + tid];
        ssS[tid] = s;
        __syncthreads();
        if (tid < 128) {
            float mu = ssS[tid] * (1.f / NN);
            float var = ssS[128 + tid] * (1.f / NN) - mu * mu;
            float sc = gamma[tid] * rsqrtf(var + EPSV);
            float sh = beta[tid] - mu * sc;
            ssS[tid] = sc;
            ssS[128 + tid] = sh;
        }
        __syncthreads();
#pragma unroll
        for (int i = 0; i < 4; ++i) {
            int q = tid + i * 256;   // 0..1023
            int row = q >> 4;
            int k8 = (q & 15) * 8;
            int rg = rowBase + row;
            if (rg >= NN) rg = NN - 1;
            bf16x8 raw = *(const bf16x8*)&Inh[(size_t)rg * HD + k8];
            unsigned short o[8];
#pragma unroll
            for (int e = 0; e < 8; ++e) {
                float v = bfu((unsigned short)raw[e]);
                v = fmaxf(v * ssS[k8 + e] + ssS[128 + k8 + e], 0.f);
                o[e] = f2bf(v);
            }
            *(bf16x8*)&Abf[row * SP + k8] = *(bf16x8*)o;
        }
    } else {
#pragma unroll
        for (int i = 0; i < 8; ++i) {
            int q = tid + i * 256;   // float4 units
            int row = q >> 5;
            int c4 = (q & 31) * 4;
            int rg = rowBase + row;
            if (rg >= NN) rg = NN - 1;
            float4 v = *(const float4*)&Inf[(size_t)rg * HD + c4];
            unsigned short* p = &Abf[row * SP + c4];
            p[0] = f2bf(v.x); p[1] = f2bf(v.y); p[2] = f2bf(v.z); p[3] = f2bf(v.w);
        }
    }
#pragma unroll
    for (int i = 0; i < 8; ++i) {
        int q = tid + i * 256;   // short8 units
        int n = q >> 4;
        int k8 = (q & 15) * 8;
        bf16x8 w = *(const bf16x8*)&Wt[n * HD + k8];
        *(bf16x8*)&WtL[n * SP + k8] = w;
    }
    __syncthreads();
    int lane = tid & 63;
    int wv = tid >> 6;
    int quad = lane >> 4;
    int lrow = wv * 16 + (lane & 15);
    f32x4 acc[8];
#pragma unroll
    for (int c = 0; c < 8; ++c) acc[c] = (f32x4){0.f, 0.f, 0.f, 0.f};
#pragma unroll
    for (int qk = 0; qk < 4; ++qk) {
        int ko = quad * 8 + qk * 32;
        bf16x8 bfr = *(const bf16x8*)&Abf[lrow * SP + ko];
#pragma unroll
        for (int c = 0; c < 8; ++c) {
            bf16x8 afr = *(const bf16x8*)&WtL[(c * 16 + (lane & 15)) * SP + ko];
            acc[c] = __builtin_amdgcn_mfma_f32_16x16x32_bf16(afr, bfr, acc[c], 0, 0, 0);
        }
    }
    int grow = rowBase + lrow;
    if (grow < NN) {
        float di = dinv[grow];
#pragma unroll
        for (int c = 0; c < 8; ++c) {
            ushort4 o;
            o.x = f2bf(acc[c][0] * di);
            o.y = f2bf(acc[c][1] * di);
            o.z = f2bf(acc[c][2] * di);
            o.w = f2bf(acc[c][3] * di);
            *(ushort4*)&Th[(size_t)grow * HD + c * 16 + quad * 4] = o;
        }
    }
}

// ---------------- Aggregate + fused BN column stats (striped, no LDS atomics) ----------------
// A(bf16)[d] = dinv[d]*(sum Ts[s] + Ts[d]) + b ; pre-round f32 values go to a
// per-wave private LDS stripe (plain float4 stores), cross-wave reduce, then
// ONE global atomicAdd per thread into statsP[blockIdx&63][256].
__global__ __launch_bounds__(256, 8) void k_aggregate(const uint4* __restrict__ T4,
                                                      const int* __restrict__ offsets,
                                                      const int* __restrict__ csr,
                                                      const float* __restrict__ dinv,
                                                      const float* __restrict__ bias,
                                                      unsigned short* __restrict__ Ah,
                                                      float* __restrict__ statsP) {
    __shared__ float sst[4][256];   // [wave][128 sums | 128 sumsq]
    int tid = threadIdx.x;
    int wv = tid >> 6;
    int l = tid & 63;
    int half = l >> 4;   // 0..3 : edge slot
    int li = l & 15;     // uint4 index within a 128-feat row
    // zero own wave's stripe (covers tail blocks where this wave writes no values)
    *(float4*)&sst[wv][4 * l] = (float4){0.f, 0.f, 0.f, 0.f};
    int d = blockIdx.x * 4 + wv;
    if (d < NN) {
        int start = offsets[d], end = offsets[d + 1];
        float a0 = 0.f, a1 = 0.f, a2 = 0.f, a3 = 0.f;
        float a4 = 0.f, a5 = 0.f, a6 = 0.f, a7 = 0.f;
        int j = start;
        for (; j + 7 < end; j += 8) {
            int s0 = csr[j + half];
            int s1 = csr[j + 4 + half];
            uint4 v0 = T4[(size_t)s0 * 16 + li];
            uint4 v1 = T4[(size_t)s1 * 16 + li];
            a0 += bf_lo(v0.x); a1 += bf_hi(v0.x); a2 += bf_lo(v0.y); a3 += bf_hi(v0.y);
            a4 += bf_lo(v0.z); a5 += bf_hi(v0.z); a6 += bf_lo(v0.w); a7 += bf_hi(v0.w);
            a0 += bf_lo(v1.x); a1 += bf_hi(v1.x); a2 += bf_lo(v1.y); a3 += bf_hi(v1.y);
            a4 += bf_lo(v1.z); a5 += bf_hi(v1.z); a6 += bf_lo(v1.w); a7 += bf_hi(v1.w);
        }
        for (; j + 3 < end; j += 4) {
            int s0 = csr[j + half];
            uint4 v0 = T4[(size_t)s0 * 16 + li];
            a0 += bf_lo(v0.x); a1 += bf_hi(v0.x); a2 += bf_lo(v0.y); a3 += bf_hi(v0.y);
            a4 += bf_lo(v0.z); a5 += bf_hi(v0.z); a6 += bf_lo(v0.w); a7 += bf_hi(v0.w);
        }
        if (j + half < end) {
            int s0 = csr[j + half];
            uint4 v0 = T4[(size_t)s0 * 16 + li];
            a0 += bf_lo(v0.x); a1 += bf_hi(v0.x); a2 += bf_lo(v0.y); a3 += bf_hi(v0.y);
            a4 += bf_lo(v0.z); a5 += bf_hi(v0.z); a6 += bf_lo(v0.w); a7 += bf_hi(v0.w);
        }
        // reduce across the 4 edge slots (lanes l, l^16, l^32, l^48)
        a0 += __shfl_xor(a0, 16); a1 += __shfl_xor(a1, 16);
        a2 += __shfl_xor(a2, 16); a3 += __shfl_xor(a3, 16);
        a4 += __shfl_xor(a4, 16); a5 += __shfl_xor(a5, 16);
        a6 += __shfl_xor(a6, 16); a7 += __shfl_xor(a7, 16);
        a0 += __shfl_xor(a0, 32); a1 += __shfl_xor(a1, 32);
        a2 += __shfl_xor(a2, 32); a3 += __shfl_xor(a3, 32);
        a4 += __shfl_xor(a4, 32); a5 += __shfl_xor(a5, 32);
        a6 += __shfl_xor(a6, 32); a7 += __shfl_xor(a7, 32);
        if (half == 0) {
            float di = dinv[d];
            uint4 vd = T4[(size_t)d * 16 + li];
            float4 bs0 = *(const float4*)&bias[8 * li];
            float4 bs1 = *(const float4*)&bias[8 * li + 4];
            float v0 = di * (a0 + bf_lo(vd.x)) + bs0.x;
            float v1 = di * (a1 + bf_hi(vd.x)) + bs0.y;
            float v2 = di * (a2 + bf_lo(vd.y)) + bs0.z;
            float v3 = di * (a3 + bf_hi(vd.y)) + bs0.w;
            float v4 = di * (a4 + bf_lo(vd.z)) + bs1.x;
            float v5 = di * (a5 + bf_hi(vd.z)) + bs1.y;
            float v6 = di * (a6 + bf_lo(vd.w)) + bs1.z;
            float v7 = di * (a7 + bf_hi(vd.w)) + bs1.w;
            int fb = 8 * li;
            *(float4*)&sst[wv][fb] = (float4){v0, v1, v2, v3};
            *(float4*)&sst[wv][fb + 4] = (float4){v4, v5, v6, v7};
            *(float4*)&sst[wv][128 + fb] = (float4){v0 * v0, v1 * v1, v2 * v2, v3 * v3};
            *(float4*)&sst[wv][128 + fb + 4] = (float4){v4 * v4, v5 * v5, v6 * v6, v7 * v7};
            unsigned short o[8];
            o[0] = f2bf(v0); o[1] = f2bf(v1); o[2] = f2bf(v2); o[3] = f2bf(v3);
            o[4] = f2bf(v4); o[5] = f2bf(v5); o[6] = f2bf(v6); o[7] = f2bf(v7);
            *(bf16x8*)&Ah[(size_t)d * HD + 8 * li] = *(bf16x8*)o;
        }
    }
    __syncthreads();
    float r = sst[0][tid] + sst[1][tid] + sst[2][tid] + sst[3][tid];
    atomicAdd(&statsP[(blockIdx.x & (NSC - 1)) * 256 + tid], r);
}

// ---------------- MLP head with fused pool + BN (one graph per block) ----------------
__global__ __launch_bounds__(128) void k_mlp(const unsigned short* __restrict__ Ah,
                                             const int* __restrict__ batch,
                                             const float* __restrict__ statsP,
                                             const float* __restrict__ gamma,
                                             const float* __restrict__ beta,
                                             const float* __restrict__ gfeat,
                                             const float* __restrict__ M1w,
                                             const float* __restrict__ M1b,
                                             const float* __restrict__ M2w,
                                             const float* __restrict__ M2b,
                                             const float* __restrict__ M3w,
                                             const float* __restrict__ M3b,
                                             float* __restrict__ out) {
    __shared__ int sb[2];
    __shared__ float ssc[128], ssh[128];
    __shared__ float zp[4][128];
    __shared__ float z[HD + GD];
    __shared__ float z1[MD];
    __shared__ float z2[MD / 2];
    int b = blockIdx.x, t = threadIdx.x;
    if (t < 2) {
        int val = b + t;
        int lo = 0, hi = NN;
        while (lo < hi) {
            int mid = (lo + hi) >> 1;
            if (batch[mid] < val) lo = mid + 1; else hi = mid;
        }
        sb[t] = lo;
    }
    // BN scales for layer-2 stats (feat t)
    float s = 0.f, q = 0.f;
    for (int c = 0; c < NSC; ++c) {
        s += statsP[c * 256 + t];
        q += statsP[c * 256 + 128 + t];
    }
    {
        float mu = s * (1.f / NN);
        float var = q * (1.f / NN) - mu * mu;
        float sc = gamma[t] * rsqrtf(var + EPSV);
        ssc[t] = sc;
        ssh[t] = beta[t] - mu * sc;
    }
    __syncthreads();
    int s0 = sb[0], s1 = sb[1];
    int grp = t >> 5, u = t & 31;
    float c0 = ssc[4 * u], c1 = ssc[4 * u + 1], c2 = ssc[4 * u + 2], c3 = ssc[4 * u + 3];
    float h0 = ssh[4 * u], h1 = ssh[4 * u + 1], h2 = ssh[4 * u + 2], h3 = ssh[4 * u + 3];
    float p0 = 0.f, p1 = 0.f, p2 = 0.f, p3 = 0.f;
    const uint2* A2 = (const uint2*)Ah;
    for (int r = s0 + grp; r < s1; r += 4) {
        uint2 v = A2[(size_t)r * 32 + u];
        p0 += fmaxf(bf_lo(v.x) * c0 + h0, 0.f);
        p1 += fmaxf(bf_hi(v.x) * c1 + h1, 0.f);
        p2 += fmaxf(bf_lo(v.y) * c2 + h2, 0.f);
        p3 += fmaxf(bf_hi(v.y) * c3 + h3, 0.f);
    }
    zp[grp][4 * u + 0] = p0;
    zp[grp][4 * u + 1] = p1;
    zp[grp][4 * u + 2] = p2;
    zp[grp][4 * u + 3] = p3;
    __syncthreads();
    float ic = 1.f / fmaxf((float)(s1 - s0), 1.f);
    z[t] = (zp[0][t] + zp[1][t] + zp[2][t] + zp[3][t]) * ic;
    if (t < GD) z[HD + t] = gfeat[b * GD + t];
    __syncthreads();
    float a = M1b[t];
    for (int k = 0; k < HD + GD; ++k) a += z[k] * M1w[k * MD + t];
    z1[t] = fmaxf(a, 0.f);
    __syncthreads();
    if (t < MD / 2) {
        float a2 = M2b[t];
        for (int k = 0; k < MD; ++k) a2 += z1[k] * M2w[k * (MD / 2) + t];
        z2[t] = fmaxf(a2, 0.f);
    }
    __syncthreads();
    if (t < 64) {
        float p = z2[t] * M3w[t];
#pragma unroll
        for (int off = 32; off; off >>= 1) p += __shfl_down(p, off);
        if (t == 0) out[b] = p + M3b[0];
    }
}

static inline size_t alg(size_t x) { return (x + 255) & ~(size_t)255; }

extern "C" void kernel_launch(void* const* d_in, const int* in_sizes, int n_in,
                              void* d_out, int out_size, void* d_ws, size_t ws_size,
                              hipStream_t stream) {
    const float* x = (const float*)d_in[0];
    const int* ei = (const int*)d_in[1];
    const int* batch = (const int*)d_in[2];
    const float* gf = (const float*)d_in[3];
    const float* W[3] = {(const float*)d_in[4], (const float*)d_in[8], (const float*)d_in[12]};
    const float* bb[3] = {(const float*)d_in[5], (const float*)d_in[9], (const float*)d_in[13]};
    const float* gg[3] = {(const float*)d_in[6], (const float*)d_in[10], (const float*)d_in[14]};
    const float* be[3] = {(const float*)d_in[7], (const float*)d_in[11], (const float*)d_in[15]};
    const float* M1w = (const float*)d_in[16];
    const float* M1b = (const float*)d_in[17];
    const float* M2w = (const float*)d_in[18];
    const float* M2b = (const float*)d_in[19];
    const float* M3w = (const float*)d_in[20];
    const float* M3b = (const float*)d_in[21];
    float* out = (float*)d_out;

    char* w = (char*)d_ws;
    int* bucket_cnt = (int*)w;    w += alg((size_t)NBK * 4);
    float* statsP = (float*)w;    w += alg((size_t)3 * NSC * 256 * 4);
    size_t zspan = (size_t)(w - (char*)d_ws);   // zero bucket_cnt+statsP in one fill
    int* offsets = (int*)w;       w += alg((size_t)(NN + 1) * 4);
    int* csr = (int*)w;           w += alg((size_t)NE * 4);
    float* dinv = (float*)w;      w += alg((size_t)NN * 4);
    unsigned short* Wt = (unsigned short*)w;  w += alg((size_t)3 * 16384 * 2);
    unsigned int* binned = (unsigned int*)w;  w += alg((size_t)NBK * BCAP * 4);
    unsigned short* Ah = (unsigned short*)w;  w += alg((size_t)NN * HD * 2);
    unsigned short* Th = (unsigned short*)w;  w += alg((size_t)NN * HD * 2);

    const int* src = ei;
    const int* dst = ei + NE;

    hipMemsetAsync(bucket_cnt, 0, zspan, stream);
    k_bin<<<(NE + 2047) / 2048, 256, 0, stream>>>(src, dst, bucket_cnt, binned);
    k_csr<<<NBK + 3, 256, 0, stream>>>(binned, bucket_cnt, offsets, dinv, csr,
                                       W[0], W[1], W[2], Wt);

    for (int L = 0; L < 3; ++L) {
        k_gemm<<<(NN + 63) / 64, 256, 0, stream>>>(x, Ah, Wt + (size_t)L * 16384, Th,
                                                   statsP + (L ? (L - 1) * NSC * 256 : 0),
                                                   gg[L ? L - 1 : 0], be[L ? L - 1 : 0],
                                                   dinv, L > 0);
        k_aggregate<<<(NN + 3) / 4, 256, 0, stream>>>((const uint4*)Th, offsets, csr,
                                                      dinv, bb[L], Ah,
                                                      statsP + (size_t)L * NSC * 256);
    }

    k_mlp<<<BG, 128, 0, stream>>>(Ah, batch, statsP + (size_t)2 * NSC * 256,
                                  gg[2], be[2], gf, M1w, M1b, M2w, M2b, M3w, M3b, out);
}

// Round 6
// 317.173 us; speedup vs baseline: 1.4615x; 1.0015x over previous
//
#include <hip/hip_runtime.h>

#define NN 50000
#define NE 800000
#define BG 512
#define HD 128
#define GD 32
#define MD 128
#define EPSV 1e-5f
#define NBK 256   // dst buckets
#define BSTR 196  // dst per bucket (196*256 = 50176 >= NN)
#define BCAP 4096 // edge capacity per bucket (mean 3136, sd ~56)
#define SP 136    // LDS row stride (shorts) for gemm tiles
#define NSC 64    // stats partial copies (contention 12500/64 ~ 195/addr)

typedef __attribute__((ext_vector_type(8))) short bf16x8;
typedef __attribute__((ext_vector_type(4))) float f32x4;

// bf16 helpers (RNE pack, cheap unpack)
static __device__ __forceinline__ unsigned short f2bf(float f) {
    unsigned int u = __float_as_uint(f);
    u += 0x7fffu + ((u >> 16) & 1u);
    return (unsigned short)(u >> 16);
}
static __device__ __forceinline__ float bfu(unsigned short v) {
    return __uint_as_float((unsigned int)v << 16);
}
static __device__ __forceinline__ float bf_lo(unsigned int v) {
    return __uint_as_float(v << 16);
}
static __device__ __forceinline__ float bf_hi(unsigned int v) {
    return __uint_as_float(v & 0xffff0000u);
}

// ---------------- Pass 1: bin edges by dst bucket ----------------
__global__ __launch_bounds__(256) void k_bin(const int* __restrict__ src,
                                             const int* __restrict__ dst,
                                             int* __restrict__ bucket_cnt,
                                             unsigned int* __restrict__ binned) {
    __shared__ int hcnt[NBK];
    __shared__ int hbase[NBK];
    int tid = threadIdx.x;
    int e0 = blockIdx.x * 2048;
    unsigned int pv[8];
    int bk[8], rk[8];
#pragma unroll
    for (int i = 0; i < 8; ++i) {
        int e = e0 + i * 256 + tid;
        if (e < NE) {
            int s = src[e];
            int d = dst[e];
            bk[i] = d / BSTR;
            pv[i] = ((unsigned int)(d - bk[i] * BSTR) << 16) | (unsigned int)s;
        } else {
            bk[i] = -1;
        }
    }
    hcnt[tid] = 0;
    __syncthreads();
#pragma unroll
    for (int i = 0; i < 8; ++i)
        if (bk[i] >= 0) rk[i] = atomicAdd(&hcnt[bk[i]], 1);
    __syncthreads();
    hbase[tid] = atomicAdd(&bucket_cnt[tid], hcnt[tid]);
    __syncthreads();
#pragma unroll
    for (int i = 0; i < 8; ++i)
        if (bk[i] >= 0)
            binned[(size_t)bk[i] * BCAP + hbase[bk[i]] + rk[i]] = pv[i];
}

// ---------------- CSR build (blocks 0..255) + W transpose (blocks 256..258) ----------------
__global__ __launch_bounds__(256) void k_csr(const unsigned int* __restrict__ binned,
                                             const int* __restrict__ bucket_cnt,
                                             int* __restrict__ offsets,
                                             float* __restrict__ dinv,
                                             int* __restrict__ csr,
                                             const float* __restrict__ W0,
                                             const float* __restrict__ W1,
                                             const float* __restrict__ W2,
                                             unsigned short* __restrict__ Wt) {
    __shared__ unsigned short sW[128 * 130];
    __shared__ int ls[256];
    __shared__ int h[BSTR];
    __shared__ int cur[BSTR];
    __shared__ int bpre_s;
    int b = blockIdx.x, t = threadIdx.x;
    if (b >= NBK) {
        const float* Wsrc = (b == NBK) ? W0 : ((b == NBK + 1) ? W1 : W2);
#pragma unroll
        for (int i = 0; i < 64; ++i) {
            int idx = i * 256 + t;
            int k = idx >> 7, n = idx & 127;
            sW[n * 130 + k] = f2bf(Wsrc[idx]);
        }
        __syncthreads();
        unsigned short* o = Wt + (size_t)(b - NBK) * 16384;
#pragma unroll
        for (int i = 0; i < 64; ++i) {
            int idx = i * 256 + t;
            int n = idx >> 7, k = idx & 127;
            o[idx] = sW[n * 130 + k];
        }
        return;
    }
    int bc = bucket_cnt[t];
    ls[t] = bc;
    __syncthreads();
    for (int off = 1; off < 256; off <<= 1) {
        int c0 = ls[t];
        int add = (t >= off) ? ls[t - off] : 0;
        __syncthreads();
        ls[t] = c0 + add;
        __syncthreads();
    }
    if (t == b) bpre_s = ls[t] - bc;
    if (t < BSTR) h[t] = 0;
    __syncthreads();
    int bpre = bpre_s;
    int nb = bucket_cnt[b];
    const unsigned int* base = binned + (size_t)b * BCAP;
    for (int e = t; e < nb; e += 256)
        atomicAdd(&h[base[e] >> 16], 1);
    __syncthreads();
    int c = (t < BSTR) ? h[t] : 0;
    ls[t] = c;
    __syncthreads();
    for (int off = 1; off < 256; off <<= 1) {
        int c0 = ls[t];
        int add = (t >= off) ? ls[t - off] : 0;
        __syncthreads();
        ls[t] = c0 + add;
        __syncthreads();
    }
    int node = b * BSTR + t;
    if (t < BSTR) {
        int excl = ls[t] - c + bpre;
        cur[t] = excl;
        if (node < NN) {
            offsets[node] = excl;
            dinv[node] = rsqrtf((float)(c + 1));  // in-degree + self loop
            if (node == NN - 1) offsets[NN] = NE;
        }
    }
    __syncthreads();
    for (int e = t; e < nb; e += 256) {
        unsigned int v = base[e];
        int pos = atomicAdd(&cur[v >> 16], 1);
        csr[pos] = (int)(v & 0xffffu);
    }
}

// ---------------- MFMA GEMM (LDS-staged): Th(bf16) = dinv[row] * (BNReLU?(In) @ W) ----------------
// BN scales derived from 64-copy partial stats (reduced here, once per block).
__global__ __launch_bounds__(256) void k_gemm(const float* __restrict__ Inf,
                                              const unsigned short* __restrict__ Inh,
                                              const unsigned short* __restrict__ Wt,
                                              unsigned short* __restrict__ Th,
                                              const float* __restrict__ statsP,
                                              const float* __restrict__ gamma,
                                              const float* __restrict__ beta,
                                              const float* __restrict__ dinv,
                                              int useBN) {
    __shared__ unsigned short Abf[64 * SP];
    __shared__ unsigned short WtL[128 * SP];
    __shared__ float ssS[256];
    int tid = threadIdx.x;
    int rowBase = blockIdx.x * 64;
    if (useBN) {
        float s = 0.f;
        for (int c = 0; c < NSC; ++c) s += statsP[c * 256 + tid];
        ssS[tid] = s;
        __syncthreads();
        if (tid < 128) {
            float mu = ssS[tid] * (1.f / NN);
            float var = ssS[128 + tid] * (1.f / NN) - mu * mu;
            float sc = gamma[tid] * rsqrtf(var + EPSV);
            float sh = beta[tid] - mu * sc;
            ssS[tid] = sc;
            ssS[128 + tid] = sh;
        }
        __syncthreads();
#pragma unroll
        for (int i = 0; i < 4; ++i) {
            int q = tid + i * 256;   // 0..1023
            int row = q >> 4;
            int k8 = (q & 15) * 8;
            int rg = rowBase + row;
            if (rg >= NN) rg = NN - 1;
            bf16x8 raw = *(const bf16x8*)&Inh[(size_t)rg * HD + k8];
            unsigned short o[8];
#pragma unroll
            for (int e = 0; e < 8; ++e) {
                float v = bfu((unsigned short)raw[e]);
                v = fmaxf(v * ssS[k8 + e] + ssS[128 + k8 + e], 0.f);
                o[e] = f2bf(v);
            }
            *(bf16x8*)&Abf[row * SP + k8] = *(bf16x8*)o;
        }
    } else {
#pragma unroll
        for (int i = 0; i < 8; ++i) {
            int q = tid + i * 256;   // float4 units
            int row = q >> 5;
            int c4 = (q & 31) * 4;
            int rg = rowBase + row;
            if (rg >= NN) rg = NN - 1;
            float4 v = *(const float4*)&Inf[(size_t)rg * HD + c4];
            unsigned short* p = &Abf[row * SP + c4];
            p[0] = f2bf(v.x); p[1] = f2bf(v.y); p[2] = f2bf(v.z); p[3] = f2bf(v.w);
        }
    }
#pragma unroll
    for (int i = 0; i < 8; ++i) {
        int q = tid + i * 256;   // short8 units
        int n = q >> 4;
        int k8 = (q & 15) * 8;
        bf16x8 w = *(const bf16x8*)&Wt[n * HD + k8];
        *(bf16x8*)&WtL[n * SP + k8] = w;
    }
    __syncthreads();
    int lane = tid & 63;
    int wv = tid >> 6;
    int quad = lane >> 4;
    int lrow = wv * 16 + (lane & 15);
    f32x4 acc[8];
#pragma unroll
    for (int c = 0; c < 8; ++c) acc[c] = (f32x4){0.f, 0.f, 0.f, 0.f};
#pragma unroll
    for (int qk = 0; qk < 4; ++qk) {
        int ko = quad * 8 + qk * 32;
        bf16x8 bfr = *(const bf16x8*)&Abf[lrow * SP + ko];
#pragma unroll
        for (int c = 0; c < 8; ++c) {
            bf16x8 afr = *(const bf16x8*)&WtL[(c * 16 + (lane & 15)) * SP + ko];
            acc[c] = __builtin_amdgcn_mfma_f32_16x16x32_bf16(afr, bfr, acc[c], 0, 0, 0);
        }
    }
    int grow = rowBase + lrow;
    if (grow < NN) {
        float di = dinv[grow];
#pragma unroll
        for (int c = 0; c < 8; ++c) {
            ushort4 o;
            o.x = f2bf(acc[c][0] * di);
            o.y = f2bf(acc[c][1] * di);
            o.z = f2bf(acc[c][2] * di);
            o.w = f2bf(acc[c][3] * di);
            *(ushort4*)&Th[(size_t)grow * HD + c * 16 + quad * 4] = o;
        }
    }
}

// ---------------- Aggregate + fused BN column stats (striped, no LDS atomics) ----------------
// 16-edge main unroll: 4 csr index loads then 4 independent uint4 row loads in
// flight per lane (latency hiding); dst self-row hoisted above the loop.
__global__ __launch_bounds__(256, 8) void k_aggregate(const uint4* __restrict__ T4,
                                                      const int* __restrict__ offsets,
                                                      const int* __restrict__ csr,
                                                      const float* __restrict__ dinv,
                                                      const float* __restrict__ bias,
                                                      unsigned short* __restrict__ Ah,
                                                      float* __restrict__ statsP) {
    __shared__ float sst[4][256];   // [wave][128 sums | 128 sumsq]
    int tid = threadIdx.x;
    int wv = tid >> 6;
    int l = tid & 63;
    int half = l >> 4;   // 0..3 : edge slot
    int li = l & 15;     // uint4 index within a 128-feat row
    // zero own wave's stripe (covers tail blocks where this wave writes no values)
    *(float4*)&sst[wv][4 * l] = (float4){0.f, 0.f, 0.f, 0.f};
    int d = blockIdx.x * 4 + wv;
    if (d < NN) {
        int start = offsets[d], end = offsets[d + 1];
        uint4 vd = T4[(size_t)d * 16 + li];   // self-row, latency hidden under gather
        float a0 = 0.f, a1 = 0.f, a2 = 0.f, a3 = 0.f;
        float a4 = 0.f, a5 = 0.f, a6 = 0.f, a7 = 0.f;
        int j = start;
        for (; j + 15 < end; j += 16) {
            int s0 = csr[j + half];
            int s1 = csr[j + 4 + half];
            int s2 = csr[j + 8 + half];
            int s3 = csr[j + 12 + half];
            uint4 v0 = T4[(size_t)s0 * 16 + li];
            uint4 v1 = T4[(size_t)s1 * 16 + li];
            uint4 v2 = T4[(size_t)s2 * 16 + li];
            uint4 v3 = T4[(size_t)s3 * 16 + li];
            a0 += bf_lo(v0.x); a1 += bf_hi(v0.x); a2 += bf_lo(v0.y); a3 += bf_hi(v0.y);
            a4 += bf_lo(v0.z); a5 += bf_hi(v0.z); a6 += bf_lo(v0.w); a7 += bf_hi(v0.w);
            a0 += bf_lo(v1.x); a1 += bf_hi(v1.x); a2 += bf_lo(v1.y); a3 += bf_hi(v1.y);
            a4 += bf_lo(v1.z); a5 += bf_hi(v1.z); a6 += bf_lo(v1.w); a7 += bf_hi(v1.w);
            a0 += bf_lo(v2.x); a1 += bf_hi(v2.x); a2 += bf_lo(v2.y); a3 += bf_hi(v2.y);
            a4 += bf_lo(v2.z); a5 += bf_hi(v2.z); a6 += bf_lo(v2.w); a7 += bf_hi(v2.w);
            a0 += bf_lo(v3.x); a1 += bf_hi(v3.x); a2 += bf_lo(v3.y); a3 += bf_hi(v3.y);
            a4 += bf_lo(v3.z); a5 += bf_hi(v3.z); a6 += bf_lo(v3.w); a7 += bf_hi(v3.w);
        }
        for (; j + 7 < end; j += 8) {
            int s0 = csr[j + half];
            int s1 = csr[j + 4 + half];
            uint4 v0 = T4[(size_t)s0 * 16 + li];
            uint4 v1 = T4[(size_t)s1 * 16 + li];
            a0 += bf_lo(v0.x); a1 += bf_hi(v0.x); a2 += bf_lo(v0.y); a3 += bf_hi(v0.y);
            a4 += bf_lo(v0.z); a5 += bf_hi(v0.z); a6 += bf_lo(v0.w); a7 += bf_hi(v0.w);
            a0 += bf_lo(v1.x); a1 += bf_hi(v1.x); a2 += bf_lo(v1.y); a3 += bf_hi(v1.y);
            a4 += bf_lo(v1.z); a5 += bf_hi(v1.z); a6 += bf_lo(v1.w); a7 += bf_hi(v1.w);
        }
        for (; j + 3 < end; j += 4) {
            int s0 = csr[j + half];
            uint4 v0 = T4[(size_t)s0 * 16 + li];
            a0 += bf_lo(v0.x); a1 += bf_hi(v0.x); a2 += bf_lo(v0.y); a3 += bf_hi(v0.y);
            a4 += bf_lo(v0.z); a5 += bf_hi(v0.z); a6 += bf_lo(v0.w); a7 += bf_hi(v0.w);
        }
        if (j + half < end) {
            int s0 = csr[j + half];
            uint4 v0 = T4[(size_t)s0 * 16 + li];
            a0 += bf_lo(v0.x); a1 += bf_hi(v0.x); a2 += bf_lo(v0.y); a3 += bf_hi(v0.y);
            a4 += bf_lo(v0.z); a5 += bf_hi(v0.z); a6 += bf_lo(v0.w); a7 += bf_hi(v0.w);
        }
        // reduce across the 4 edge slots (lanes l, l^16, l^32, l^48)
        a0 += __shfl_xor(a0, 16); a1 += __shfl_xor(a1, 16);
        a2 += __shfl_xor(a2, 16); a3 += __shfl_xor(a3, 16);
        a4 += __shfl_xor(a4, 16); a5 += __shfl_xor(a5, 16);
        a6 += __shfl_xor(a6, 16); a7 += __shfl_xor(a7, 16);
        a0 += __shfl_xor(a0, 32); a1 += __shfl_xor(a1, 32);
        a2 += __shfl_xor(a2, 32); a3 += __shfl_xor(a3, 32);
        a4 += __shfl_xor(a4, 32); a5 += __shfl_xor(a5, 32);
        a6 += __shfl_xor(a6, 32); a7 += __shfl_xor(a7, 32);
        if (half == 0) {
            float di = dinv[d];
            float4 bs0 = *(const float4*)&bias[8 * li];
            float4 bs1 = *(const float4*)&bias[8 * li + 4];
            float v0 = di * (a0 + bf_lo(vd.x)) + bs0.x;
            float v1 = di * (a1 + bf_hi(vd.x)) + bs0.y;
            float v2 = di * (a2 + bf_lo(vd.y)) + bs0.z;
            float v3 = di * (a3 + bf_hi(vd.y)) + bs0.w;
            float v4 = di * (a4 + bf_lo(vd.z)) + bs1.x;
            float v5 = di * (a5 + bf_hi(vd.z)) + bs1.y;
            float v6 = di * (a6 + bf_lo(vd.w)) + bs1.z;
            float v7 = di * (a7 + bf_hi(vd.w)) + bs1.w;
            int fb = 8 * li;
            *(float4*)&sst[wv][fb] = (float4){v0, v1, v2, v3};
            *(float4*)&sst[wv][fb + 4] = (float4){v4, v5, v6, v7};
            *(float4*)&sst[wv][128 + fb] = (float4){v0 * v0, v1 * v1, v2 * v2, v3 * v3};
            *(float4*)&sst[wv][128 + fb + 4] = (float4){v4 * v4, v5 * v5, v6 * v6, v7 * v7};
            unsigned short o[8];
            o[0] = f2bf(v0); o[1] = f2bf(v1); o[2] = f2bf(v2); o[3] = f2bf(v3);
            o[4] = f2bf(v4); o[5] = f2bf(v5); o[6] = f2bf(v6); o[7] = f2bf(v7);
            *(bf16x8*)&Ah[(size_t)d * HD + 8 * li] = *(bf16x8*)o;
        }
    }
    __syncthreads();
    float r = sst[0][tid] + sst[1][tid] + sst[2][tid] + sst[3][tid];
    atomicAdd(&statsP[(blockIdx.x & (NSC - 1)) * 256 + tid], r);
}

// ---------------- MLP head with fused pool + BN (one graph per block) ----------------
__global__ __launch_bounds__(128) void k_mlp(const unsigned short* __restrict__ Ah,
                                             const int* __restrict__ batch,
                                             const float* __restrict__ statsP,
                                             const float* __restrict__ gamma,
                                             const float* __restrict__ beta,
                                             const float* __restrict__ gfeat,
                                             const float* __restrict__ M1w,
                                             const float* __restrict__ M1b,
                                             const float* __restrict__ M2w,
                                             const float* __restrict__ M2b,
                                             const float* __restrict__ M3w,
                                             const float* __restrict__ M3b,
                                             float* __restrict__ out) {
    __shared__ int sb[2];
    __shared__ float ssc[128], ssh[128];
    __shared__ float zp[4][128];
    __shared__ float z[HD + GD];
    __shared__ float z1[MD];
    __shared__ float z2[MD / 2];
    int b = blockIdx.x, t = threadIdx.x;
    if (t < 2) {
        int val = b + t;
        int lo = 0, hi = NN;
        while (lo < hi) {
            int mid = (lo + hi) >> 1;
            if (batch[mid] < val) lo = mid + 1; else hi = mid;
        }
        sb[t] = lo;
    }
    // BN scales for layer-2 stats (feat t)
    float s = 0.f, q = 0.f;
    for (int c = 0; c < NSC; ++c) {
        s += statsP[c * 256 + t];
        q += statsP[c * 256 + 128 + t];
    }
    {
        float mu = s * (1.f / NN);
        float var = q * (1.f / NN) - mu * mu;
        float sc = gamma[t] * rsqrtf(var + EPSV);
        ssc[t] = sc;
        ssh[t] = beta[t] - mu * sc;
    }
    __syncthreads();
    int s0 = sb[0], s1 = sb[1];
    int grp = t >> 5, u = t & 31;
    float c0 = ssc[4 * u], c1 = ssc[4 * u + 1], c2 = ssc[4 * u + 2], c3 = ssc[4 * u + 3];
    float h0 = ssh[4 * u], h1 = ssh[4 * u + 1], h2 = ssh[4 * u + 2], h3 = ssh[4 * u + 3];
    float p0 = 0.f, p1 = 0.f, p2 = 0.f, p3 = 0.f;
    const uint2* A2 = (const uint2*)Ah;
    for (int r = s0 + grp; r < s1; r += 4) {
        uint2 v = A2[(size_t)r * 32 + u];
        p0 += fmaxf(bf_lo(v.x) * c0 + h0, 0.f);
        p1 += fmaxf(bf_hi(v.x) * c1 + h1, 0.f);
        p2 += fmaxf(bf_lo(v.y) * c2 + h2, 0.f);
        p3 += fmaxf(bf_hi(v.y) * c3 + h3, 0.f);
    }
    zp[grp][4 * u + 0] = p0;
    zp[grp][4 * u + 1] = p1;
    zp[grp][4 * u + 2] = p2;
    zp[grp][4 * u + 3] = p3;
    __syncthreads();
    float ic = 1.f / fmaxf((float)(s1 - s0), 1.f);
    z[t] = (zp[0][t] + zp[1][t] + zp[2][t] + zp[3][t]) * ic;
    if (t < GD) z[HD + t] = gfeat[b * GD + t];
    __syncthreads();
    float a = M1b[t];
    for (int k = 0; k < HD + GD; ++k) a += z[k] * M1w[k * MD + t];
    z1[t] = fmaxf(a, 0.f);
    __syncthreads();
    if (t < MD / 2) {
        float a2 = M2b[t];
        for (int k = 0; k < MD; ++k) a2 += z1[k] * M2w[k * (MD / 2) + t];
        z2[t] = fmaxf(a2, 0.f);
    }
    __syncthreads();
    if (t < 64) {
        float p = z2[t] * M3w[t];
#pragma unroll
        for (int off = 32; off; off >>= 1) p += __shfl_down(p, off);
        if (t == 0) out[b] = p + M3b[0];
    }
}

static inline size_t alg(size_t x) { return (x + 255) & ~(size_t)255; }

extern "C" void kernel_launch(void* const* d_in, const int* in_sizes, int n_in,
                              void* d_out, int out_size, void* d_ws, size_t ws_size,
                              hipStream_t stream) {
    const float* x = (const float*)d_in[0];
    const int* ei = (const int*)d_in[1];
    const int* batch = (const int*)d_in[2];
    const float* gf = (const float*)d_in[3];
    const float* W[3] = {(const float*)d_in[4], (const float*)d_in[8], (const float*)d_in[12]};
    const float* bb[3] = {(const float*)d_in[5], (const float*)d_in[9], (const float*)d_in[13]};
    const float* gg[3] = {(const float*)d_in[6], (const float*)d_in[10], (const float*)d_in[14]};
    const float* be[3] = {(const float*)d_in[7], (const float*)d_in[11], (const float*)d_in[15]};
    const float* M1w = (const float*)d_in[16];
    const float* M1b = (const float*)d_in[17];
    const float* M2w = (const float*)d_in[18];
    const float* M2b = (const float*)d_in[19];
    const float* M3w = (const float*)d_in[20];
    const float* M3b = (const float*)d_in[21];
    float* out = (float*)d_out;

    char* w = (char*)d_ws;
    int* bucket_cnt = (int*)w;    w += alg((size_t)NBK * 4);
    float* statsP = (float*)w;    w += alg((size_t)3 * NSC * 256 * 4);
    size_t zspan = (size_t)(w - (char*)d_ws);   // zero bucket_cnt+statsP in one fill
    int* offsets = (int*)w;       w += alg((size_t)(NN + 1) * 4);
    int* csr = (int*)w;           w += alg((size_t)NE * 4);
    float* dinv = (float*)w;      w += alg((size_t)NN * 4);
    unsigned short* Wt = (unsigned short*)w;  w += alg((size_t)3 * 16384 * 2);
    unsigned int* binned = (unsigned int*)w;  w += alg((size_t)NBK * BCAP * 4);
    unsigned short* Ah = (unsigned short*)w;  w += alg((size_t)NN * HD * 2);
    unsigned short* Th = (unsigned short*)w;  w += alg((size_t)NN * HD * 2);

    const int* src = ei;
    const int* dst = ei + NE;

    hipMemsetAsync(bucket_cnt, 0, zspan, stream);
    k_bin<<<(NE + 2047) / 2048, 256, 0, stream>>>(src, dst, bucket_cnt, binned);
    k_csr<<<NBK + 3, 256, 0, stream>>>(binned, bucket_cnt, offsets, dinv, csr,
                                       W[0], W[1], W[2], Wt);

    for (int L = 0; L < 3; ++L) {
        k_gemm<<<(NN + 63) / 64, 256, 0, stream>>>(x, Ah, Wt + (size_t)L * 16384, Th,
                                                   statsP + (L ? (L - 1) * NSC * 256 : 0),
                                                   gg[L ? L - 1 : 0], be[L ? L - 1 : 0],
                                                   dinv, L > 0);
        k_aggregate<<<(NN + 3) / 4, 256, 0, stream>>>((const uint4*)Th, offsets, csr,
                                                      dinv, bb[L], Ah,
                                                      statsP + (size_t)L * NSC * 256);
    }

    k_mlp<<<BG, 128, 0, stream>>>(Ah, batch, statsP + (size_t)2 * NSC * 256,
                                  gg[2], be[2], gf, M1w, M1b, M2w, M2b, M3w, M3b, out);
}